// Round 1
// baseline (369.981 us; speedup 1.0000x reference)
//
#include <hip/hip_runtime.h>
#include <math.h>

#define NN 2048
#define FF 128
#define UU 128
#define FE 16
#define DEG 64

// ---------------- Kernel A: hl = ns @ Wl, hr = ns @ Wr ----------------
// 256 threads/block, 16 nodes/block, grid = 128 blocks.
__global__ __launch_bounds__(256) void gemm_hlr(
    const float* __restrict__ ns, const float* __restrict__ Wl,
    const float* __restrict__ Wr, float* __restrict__ hl, float* __restrict__ hr)
{
    __shared__ float sns[16][FF];
    const int nb = blockIdx.x * 16;
    const int tid = threadIdx.x;
    for (int i = tid; i < 16 * FF; i += 256) {
        sns[i >> 7][i & 127] = ns[(size_t)(nb + (i >> 7)) * FF + (i & 127)];
    }
    __syncthreads();
    const int u = tid & 127;
    const int ng = tid >> 7;  // 0 or 1 -> node group of 8
    float accl[8] = {0.f, 0.f, 0.f, 0.f, 0.f, 0.f, 0.f, 0.f};
    float accr[8] = {0.f, 0.f, 0.f, 0.f, 0.f, 0.f, 0.f, 0.f};
    for (int k = 0; k < FF; ++k) {
        const float wl = Wl[k * UU + u];
        const float wr = Wr[k * UU + u];
#pragma unroll
        for (int j = 0; j < 8; ++j) {
            const float a = sns[ng * 8 + j][k];  // broadcast within wave
            accl[j] += a * wl;
            accr[j] += a * wr;
        }
    }
#pragma unroll
    for (int j = 0; j < 8; ++j) {
        hl[(size_t)(nb + ng * 8 + j) * UU + u] = accl[j];
        hr[(size_t)(nb + ng * 8 + j) * UU + u] = accr[j];
    }
}

// ---------------- Kernel B: al[n], ar[n] per-node attention scalars ----------------
// 128 threads/block, one node per block, grid = 2048.
__global__ __launch_bounds__(128) void node_attn(
    const float* __restrict__ hl, const float* __restrict__ hr,
    const float* __restrict__ Wa, float* __restrict__ al, float* __restrict__ ar)
{
    const int n = blockIdx.x;
    const int u = threadIdx.x;
    float x = hl[(size_t)n * UU + u];
    float y = hr[(size_t)n * UU + u];
    x = (x > 0.f ? x : 0.2f * x) * Wa[u];
    y = (y > 0.f ? y : 0.2f * y) * Wa[UU + u];
#pragma unroll
    for (int o = 32; o > 0; o >>= 1) { x += __shfl_xor(x, o); y += __shfl_xor(y, o); }
    __shared__ float sx[2], sy[2];
    if ((u & 63) == 0) { sx[u >> 6] = x; sy[u >> 6] = y; }
    __syncthreads();
    if (u == 0) { al[n] = sx[0] + sx[1]; ar[n] = sy[0] + sy[1]; }
}

// ---------------- Kernel C: edge scores + softmax + output ----------------
// One block per src node (segments are contiguous blocks of DEG=64 edges).
// 128 threads: wave 0 computes the 64 edge scores; then all 128 threads
// (one per output unit) accumulate sum_e attn_e * hr[dst_e][u].
__global__ __launch_bounds__(128) void edge_out(
    const float* __restrict__ hr, const float* __restrict__ al,
    const float* __restrict__ ar, const int* __restrict__ edges,
    const float* __restrict__ ef, const float* __restrict__ We,
    const float* __restrict__ Wa, float* __restrict__ out)
{
    const int b = blockIdx.x;        // segment index == src node (src sorted, DEG each)
    const int tid = threadIdx.x;
    __shared__ float wef[FE];        // w_ef = W_edge @ Wa[256:272]
    __shared__ float sattn[DEG];
    __shared__ int   sdst[DEG];
    __shared__ int   s_src;

    if (tid < FE) {
        float s = 0.f;
#pragma unroll
        for (int j = 0; j < FE; ++j) s += We[tid * FE + j] * Wa[2 * UU + j];
        wef[tid] = s;
    }
    __syncthreads();

    if (tid < DEG) {
        const int e   = b * DEG + tid;
        const int src = edges[2 * e];
        const int dst = edges[2 * e + 1];
        if (tid == 0) s_src = src;
        const float4* efp = (const float4*)(ef + ((size_t)src * NN + dst) * FE);
        float s = al[src] + ar[dst];
#pragma unroll
        for (int q = 0; q < 4; ++q) {
            const float4 v = efp[q];
            s += v.x * wef[4 * q + 0] + v.y * wef[4 * q + 1]
               + v.z * wef[4 * q + 2] + v.w * wef[4 * q + 3];
        }
        s = fminf(fmaxf(s, -2.f), 2.f);
        const float sc = expf(s);
        float tot = sc;
#pragma unroll
        for (int o = 32; o > 0; o >>= 1) tot += __shfl_xor(tot, o);
        sattn[tid] = sc / tot;
        sdst[tid]  = dst;
    }
    __syncthreads();

    const int u = tid;  // 0..127 output unit
    float acc = 0.f;
#pragma unroll 8
    for (int e = 0; e < DEG; ++e) {
        acc += sattn[e] * hr[(size_t)sdst[e] * UU + u];
    }
    out[(size_t)s_src * UU + u] = acc;
}

extern "C" void kernel_launch(void* const* d_in, const int* in_sizes, int n_in,
                              void* d_out, int out_size, void* d_ws, size_t ws_size,
                              hipStream_t stream) {
    const float* ns  = (const float*)d_in[0];
    const int*   edg = (const int*)d_in[1];
    const float* ef  = (const float*)d_in[2];
    const float* Wl  = (const float*)d_in[3];
    const float* Wr  = (const float*)d_in[4];
    const float* Wa  = (const float*)d_in[5];
    const float* We  = (const float*)d_in[6];
    float* out = (float*)d_out;

    // workspace layout
    float* hl = (float*)d_ws;                       // N*U floats = 1 MB
    float* hr = hl + (size_t)NN * UU;               // 1 MB
    float* al = hr + (size_t)NN * UU;               // 8 KB
    float* ar = al + NN;                            // 8 KB

    gemm_hlr<<<NN / 16, 256, 0, stream>>>(ns, Wl, Wr, hl, hr);
    node_attn<<<NN, 128, 0, stream>>>(hl, hr, Wa, al, ar);
    edge_out<<<NN, 128, 0, stream>>>(hr, al, ar, edg, ef, We, Wa, out);
}

// Round 2
// 331.695 us; speedup vs baseline: 1.1154x; 1.1154x over previous
//
#include <hip/hip_runtime.h>
#include <math.h>

#define NN 2048
#define FF 128
#define UU 128
#define FE 16
#define DEG 64

// ---------------- Kernel 1: hl/hr GEMM + al/ar reduction + wef ----------------
// 256 blocks x 256 threads, 8 nodes per block. hl never touches memory:
// al[n] = sum_u lrelu(hl[n][u]) * Wa[u] is reduced in-block.
__global__ __launch_bounds__(256) void prep(
    const float* __restrict__ ns, const float* __restrict__ Wl,
    const float* __restrict__ Wr, const float* __restrict__ Wa,
    const float* __restrict__ We,
    float* __restrict__ hr, float* __restrict__ al, float* __restrict__ ar,
    float* __restrict__ wef)
{
    __shared__ float sns[8][FF];
    __shared__ float swl[4][4], swr[4][4];
    const int nb  = blockIdx.x * 8;
    const int tid = threadIdx.x;
    // cooperative load: 8*128 floats = 256 float4, one per thread
    {
        const int idx = tid * 4;
        ((float4*)&sns[idx >> 7][idx & 127])[0] =
            ((const float4*)(ns + (size_t)nb * FF))[tid];
    }
    __syncthreads();

    const int u  = tid & 127;
    const int ng = tid >> 7;           // node group: nodes ng*4 .. ng*4+3
    float accl[4] = {0.f, 0.f, 0.f, 0.f};
    float accr[4] = {0.f, 0.f, 0.f, 0.f};
#pragma unroll 4
    for (int k = 0; k < FF; ++k) {
        const float wl = Wl[k * UU + u];
        const float wr = Wr[k * UU + u];
#pragma unroll
        for (int j = 0; j < 4; ++j) {
            const float a = sns[ng * 4 + j][k];   // wave-uniform broadcast
            accl[j] += a * wl;
            accr[j] += a * wr;
        }
    }

    // write hr, fold leaky_relu * Wa into per-node partials
    const float wa_l = Wa[u];
    const float wa_r = Wa[UU + u];
    float xl[4], xr[4];
#pragma unroll
    for (int j = 0; j < 4; ++j) {
        hr[(size_t)(nb + ng * 4 + j) * UU + u] = accr[j];
        const float l = accl[j];
        const float r = accr[j];
        xl[j] = (l > 0.f ? l : 0.2f * l) * wa_l;
        xr[j] = (r > 0.f ? r : 0.2f * r) * wa_r;
    }
    // wave reduction (64 lanes) of the 8 values
#pragma unroll
    for (int o = 32; o > 0; o >>= 1) {
#pragma unroll
        for (int j = 0; j < 4; ++j) {
            xl[j] += __shfl_xor(xl[j], o);
            xr[j] += __shfl_xor(xr[j], o);
        }
    }
    const int wave = tid >> 6;   // 0..3 ; waves 2*ng, 2*ng+1 cover node group ng
    if ((tid & 63) == 0) {
#pragma unroll
        for (int j = 0; j < 4; ++j) { swl[wave][j] = xl[j]; swr[wave][j] = xr[j]; }
    }
    __syncthreads();
    if (tid < 8) {
        const int g = tid >> 2, j = tid & 3;
        al[nb + tid] = swl[2 * g][j] + swl[2 * g + 1][j];
        ar[nb + tid] = swr[2 * g][j] + swr[2 * g + 1][j];
    }
    // wef = W_edge @ Wa[256:272], computed once by block 0
    if (blockIdx.x == 0 && tid < FE) {
        float s = 0.f;
#pragma unroll
        for (int j = 0; j < FE; ++j) s += We[tid * FE + j] * Wa[2 * UU + j];
        wef[tid] = s;
    }
}

// ---------------- Kernel 2: edge scores + softmax + output ----------------
// One block per src node (src == blockIdx since src = repeat(arange(N), DEG)).
__global__ __launch_bounds__(128) void edge_out(
    const float* __restrict__ hr, const float* __restrict__ al,
    const float* __restrict__ ar, const int* __restrict__ edges,
    const float* __restrict__ ef, const float* __restrict__ wef,
    float* __restrict__ out)
{
    const int b   = blockIdx.x;      // src node
    const int tid = threadIdx.x;
    __shared__ float sattn[DEG];
    __shared__ int   sdst[DEG];

    if (tid < DEG) {
        const int dst = edges[2 * (b * DEG + tid) + 1];
        const float4* efp = (const float4*)(ef + ((size_t)b * NN + dst) * FE);
        // wef loads are lane-uniform -> scalar loads, L2-resident
        float s = al[b] + ar[dst];
#pragma unroll
        for (int q = 0; q < 4; ++q) {
            const float4 v = efp[q];
            s += v.x * wef[4 * q + 0] + v.y * wef[4 * q + 1]
               + v.z * wef[4 * q + 2] + v.w * wef[4 * q + 3];
        }
        s = fminf(fmaxf(s, -2.f), 2.f);
        const float sc = expf(s);
        float tot = sc;
#pragma unroll
        for (int o = 32; o > 0; o >>= 1) tot += __shfl_xor(tot, o);
        sattn[tid] = sc / tot;
        sdst[tid]  = dst;
    }
    __syncthreads();

    const int u = tid;   // output unit 0..127
    float acc = 0.f;
#pragma unroll 8
    for (int e = 0; e < DEG; ++e) {
        acc += sattn[e] * hr[(size_t)sdst[e] * UU + u];
    }
    out[(size_t)b * UU + u] = acc;
}

extern "C" void kernel_launch(void* const* d_in, const int* in_sizes, int n_in,
                              void* d_out, int out_size, void* d_ws, size_t ws_size,
                              hipStream_t stream) {
    const float* ns  = (const float*)d_in[0];
    const int*   edg = (const int*)d_in[1];
    const float* ef  = (const float*)d_in[2];
    const float* Wl  = (const float*)d_in[3];
    const float* Wr  = (const float*)d_in[4];
    const float* Wa  = (const float*)d_in[5];
    const float* We  = (const float*)d_in[6];
    float* out = (float*)d_out;

    float* hr  = (float*)d_ws;              // 1 MB
    float* al  = hr + (size_t)NN * UU;      // 8 KB
    float* ar  = al + NN;                   // 8 KB
    float* wef = ar + NN;                   // 64 B

    prep<<<NN / 8, 256, 0, stream>>>(ns, Wl, Wr, Wa, We, hr, al, ar, wef);
    edge_out<<<NN, 128, 0, stream>>>(hr, al, ar, edg, ef, wef, out);
}